// Round 1
// baseline (690.729 us; speedup 1.0000x reference)
//
#include <hip/hip_runtime.h>

// SubdivideMeshes: verts (N,V,3) f32, faces (F,3) i32, edges (E,2) i32,
// face_to_edge (F,3) i32.
// Out (flat f32): new_verts (N, V+E, 3) then new_faces (4F, 3) as floats
// (indices < 2^24, exact in f32).

#define GRID_S 1024
#define V_CONST (GRID_S * GRID_S)  // 1048576

// Kernel 1: copy verts into the head of each batch's new_verts block.
// dst row stride (V+E)*3 is odd -> only 4B alignment guaranteed; scalar copy.
__global__ void copy_verts_k(const float* __restrict__ verts,
                             float* __restrict__ out,
                             int perBatch,      // V*3
                             int rowStride3,    // (V+E)*3
                             int total) {       // N*V*3
    int i = blockIdx.x * blockDim.x + threadIdx.x;
    if (i >= total) return;
    int n = i / perBatch;            // magic-mul, compile-time-ish constant div
    int r = i - n * perBatch;
    out[n * rowStride3 + r] = verts[i];
}

// Kernel 2: edge midpoints. blockIdx.y = batch index.
__global__ void midpoints_k(const float* __restrict__ verts,
                            const int* __restrict__ edges,
                            float* __restrict__ out,
                            int E,
                            int rowStride3) {
    int e = blockIdx.x * blockDim.x + threadIdx.x;
    if (e >= E) return;
    int n = blockIdx.y;
    int v0 = edges[2 * e];
    int v1 = edges[2 * e + 1];
    const float* b = verts + n * (V_CONST * 3);
    float x = 0.5f * (b[3 * v0 + 0] + b[3 * v1 + 0]);
    float y = 0.5f * (b[3 * v0 + 1] + b[3 * v1 + 1]);
    float z = 0.5f * (b[3 * v0 + 2] + b[3 * v1 + 2]);
    int o = n * rowStride3 + (V_CONST + e) * 3;
    out[o + 0] = x;
    out[o + 1] = y;
    out[o + 2] = z;
}

// Kernel 3: new faces. pytorch3d SubdivideMeshes ordering:
//   f0 = [v0, e2+V, e1+V]; f1 = [v1, e0+V, e2+V]; f2 = [v2, e1+V, e0+V]; f3 = [e0+V,e1+V,e2+V]
// concatenated along axis 0: [f0; f1; f2; f3], each F rows.
__global__ void faces_k(const int* __restrict__ faces,
                        const int* __restrict__ fte,
                        float* __restrict__ out,
                        int F,
                        int baseOut) {  // N*(V+E)*3
    int f = blockIdx.x * blockDim.x + threadIdx.x;
    if (f >= F) return;
    int a = faces[3 * f + 0];
    int b = faces[3 * f + 1];
    int c = faces[3 * f + 2];
    int e0 = fte[3 * f + 0] + V_CONST;
    int e1 = fte[3 * f + 1] + V_CONST;
    int e2 = fte[3 * f + 2] + V_CONST;
    float* o0 = out + baseOut + 3 * f;
    float* o1 = o0 + 3 * F;
    float* o2 = o1 + 3 * F;
    float* o3 = o2 + 3 * F;
    o0[0] = (float)a;  o0[1] = (float)e2; o0[2] = (float)e1;
    o1[0] = (float)b;  o1[1] = (float)e0; o1[2] = (float)e2;
    o2[0] = (float)c;  o2[1] = (float)e1; o2[2] = (float)e0;
    o3[0] = (float)e0; o3[1] = (float)e1; o3[2] = (float)e2;
}

extern "C" void kernel_launch(void* const* d_in, const int* in_sizes, int n_in,
                              void* d_out, int out_size, void* d_ws, size_t ws_size,
                              hipStream_t stream) {
    const float* verts = (const float*)d_in[0];
    const int* faces   = (const int*)d_in[1];
    const int* edges   = (const int*)d_in[2];
    const int* fte     = (const int*)d_in[3];
    float* out = (float*)d_out;

    const int F = in_sizes[1] / 3;
    const int E = in_sizes[2] / 2;
    const int N = in_sizes[0] / (V_CONST * 3);

    const int perBatch   = V_CONST * 3;          // 3,145,728
    const int rowStride3 = (V_CONST + E) * 3;    // per-batch new_verts stride
    const int totalCopy  = N * perBatch;         // 25,165,824
    const int baseOut    = N * rowStride3;       // start of new_faces region

    {
        int threads = 256;
        int blocks = (totalCopy + threads - 1) / threads;
        copy_verts_k<<<blocks, threads, 0, stream>>>(verts, out, perBatch,
                                                     rowStride3, totalCopy);
    }
    {
        dim3 block(256);
        dim3 grid((E + 255) / 256, N);
        midpoints_k<<<grid, block, 0, stream>>>(verts, edges, out, E, rowStride3);
    }
    {
        int threads = 256;
        int blocks = (F + threads - 1) / threads;
        faces_k<<<blocks, threads, 0, stream>>>(faces, fte, out, F, baseOut);
    }
}